// Round 1
// baseline (370.410 us; speedup 1.0000x reference)
//
#include <hip/hip_runtime.h>
#include <hip/hip_bf16.h>

typedef __attribute__((ext_vector_type(8))) short short8;     // 8 bf16 (4 VGPRs) MFMA frag
typedef __attribute__((ext_vector_type(4))) float f32x4;
typedef __attribute__((ext_vector_type(4))) unsigned int uint4v;

#define NROW 29
#define CCH 64
#define XSTRIDE 1856        // 29*64 floats per edge
#define N0SQ (448*448)
#define N1SQ (768*768)
#define N2SQ (640*640)

// m-order -> lp-order row permutation (TO_M); inverse handled by storing m-row r to lp-row TO_M[r]
__constant__ int d_TO_M[29] = {0,2,6,11,16,21,26, 3,7,12,17,22,27, 1,5,10,15,20,25,
                               8,13,18,23,28, 4,9,14,19,24};

__device__ __forceinline__ short f2bf(float f) {
    __hip_bfloat16 h = __float2bfloat16(f);
    return __builtin_bit_cast(short, h);
}

// Build effective bf16 weights in ws:
//  Wb0[n*448+k] = W0[n][k]
//  Wb1[n*768+k]: [[Wr,-Wi],[Wi,Wr]] from W1 (Wr=W1[0:384], Wi=W1[384:768]), layout [n][k]
//  Wb2 likewise with half=320
__global__ __launch_bounds__(256) void prep_weights(const float* __restrict__ W0,
                                                    const float* __restrict__ W1,
                                                    const float* __restrict__ W2,
                                                    short* __restrict__ ws) {
    int idx = blockIdx.x * 256 + threadIdx.x;
    if (idx < N0SQ) {
        ws[idx] = f2bf(W0[idx]);
        return;
    }
    idx -= N0SQ;
    if (idx < N1SQ) {
        int n = idx / 768, k = idx % 768;
        int no = n / 384, ni = n % 384;
        int ko = k / 384, ki = k % 384;
        float v;
        if (no == ko)      v =  W1[ni * 384 + ki];          // Wr on diagonal
        else if (no == 0)  v = -W1[(384 + ni) * 384 + ki];  // -Wi
        else               v =  W1[(384 + ni) * 384 + ki];  // +Wi
        ws[N0SQ + idx] = f2bf(v);
        return;
    }
    idx -= N1SQ;
    if (idx < N2SQ) {
        int n = idx / 640, k = idx % 640;
        int no = n / 320, ni = n % 320;
        int ko = k / 320, ki = k % 320;
        float v;
        if (no == ko)      v =  W2[ni * 320 + ki];
        else if (no == 0)  v = -W2[(320 + ni) * 320 + ki];
        else               v =  W2[(320 + ni) * 320 + ki];
        ws[N0SQ + N1SQ + idx] = f2bf(v);
    }
}

// 128(edges) x 128(out cols) tile GEMM, BK=64, 4 waves each 64x64, mfma 16x16x32 bf16.
// 15 n-tiles span the 3 weight blocks: [0,4)=blk0(448), [4,10)=blk1(768), [10,15)=blk2(640).
#define LDS_STRIDE 72   // 64 + 8 bf16 pad: 144B row stride -> 2-way-max bank aliasing (free)

__global__ __launch_bounds__(256) void so2_gemm(const float* __restrict__ x,
                                                const float* __restrict__ b0,
                                                const short* __restrict__ wsW,
                                                float* __restrict__ out,
                                                int E, int nwg) {
    // bijective XCD chunk swizzle (m204): contiguous wgid range per XCD -> etile's
    // 15 n-tiles co-resident on one XCD's L2 (A panel fetched from HBM once)
    int orig = blockIdx.x;
    int q = nwg >> 3, r = nwg & 7;
    int xcd = orig & 7, pos = orig >> 3;
    int wgid = (xcd < r ? xcd * (q + 1) : r * (q + 1) + (xcd - r) * q) + pos;

    int etile = wgid / 15;
    int ncol  = wgid % 15;

    int blk, ntl;
    if (ncol < 4)       { blk = 0; ntl = ncol; }
    else if (ncol < 10) { blk = 1; ntl = ncol - 4; }
    else                { blk = 2; ntl = ncol - 10; }
    const int Kb     = (blk == 0) ? 448 : (blk == 1) ? 768 : 640;   // = Nb (square blocks)
    const int ksteps = Kb >> 6;
    const int kbase  = (blk == 0) ? 0 : (blk == 1) ? 7 : 19;        // m-row base (in & out)
    const int nrows  = (blk == 0) ? 7 : (blk == 1) ? 12 : 10;
    const long woff  = (blk == 0) ? 0 : (blk == 1) ? (long)N0SQ : (long)(N0SQ + N1SQ);
    const short* Wb  = wsW + woff;

    __shared__ short Alds[128 * LDS_STRIDE];
    __shared__ short Blds[128 * LDS_STRIDE];

    const int tid  = threadIdx.x;
    const int w    = tid >> 6, lane = tid & 63;
    const int wr   = w >> 1,   wc   = w & 1;
    const int lrow = lane & 15, lk  = lane >> 4;
    const int ebase = etile * 128;

    f32x4 acc[4][4] = {};

    // staging registers (one k-step in flight)
    f32x4 a0[4], a1[4];
    uint4v breg[4];

    auto load_regs = [&](int kt) {
        int g = d_TO_M[kbase + kt];                      // gathered lp-row for this k-step
        const float* asrc = x + (size_t)g * CCH;
#pragma unroll
        for (int i = 0; i < 4; ++i) {
            int item = i * 256 + tid;
            int row = item >> 3, ch0 = (item & 7) << 3;
            int e = ebase + row;
            if (e < E) {
                const float* p = asrc + (size_t)e * XSTRIDE + ch0;
                a0[i] = *(const f32x4*)p;
                a1[i] = *(const f32x4*)(p + 4);
            } else {
                a0[i] = f32x4{0.f, 0.f, 0.f, 0.f};
                a1[i] = f32x4{0.f, 0.f, 0.f, 0.f};
            }
        }
        const short* bsrc = Wb + kt * 64;
#pragma unroll
        for (int i = 0; i < 4; ++i) {
            int item = i * 256 + tid;
            int row = item >> 3, k0 = (item & 7) << 3;
            int n = ntl * 128 + row;
            if (n < Kb) {
                breg[i] = *(const uint4v*)(bsrc + (size_t)n * Kb + k0);
            } else {
                breg[i] = uint4v{0u, 0u, 0u, 0u};        // block0 tail tile: zero rows
            }
        }
    };

    auto write_lds = [&]() {
#pragma unroll
        for (int i = 0; i < 4; ++i) {
            int item = i * 256 + tid;
            int row = item >> 3, ch0 = (item & 7) << 3;
            short8 hv;
#pragma unroll
            for (int j = 0; j < 4; ++j) hv[j]     = f2bf(a0[i][j]);
#pragma unroll
            for (int j = 0; j < 4; ++j) hv[4 + j] = f2bf(a1[i][j]);
            *(short8*)&Alds[row * LDS_STRIDE + ch0] = hv;
        }
#pragma unroll
        for (int i = 0; i < 4; ++i) {
            int item = i * 256 + tid;
            int row = item >> 3, k0 = (item & 7) << 3;
            *(uint4v*)&Blds[row * LDS_STRIDE + k0] = breg[i];
        }
    };

    load_regs(0);
    for (int kt = 0; kt < ksteps; ++kt) {
        __syncthreads();                 // prev iter's ds_reads done (WAR)
        write_lds();
        if (kt + 1 < ksteps) load_regs(kt + 1);   // prefetch overlaps compute below
        __syncthreads();                 // tile visible (RAW)
#pragma unroll
        for (int ks = 0; ks < 2; ++ks) {
            short8 af[4], bf[4];
#pragma unroll
            for (int mf = 0; mf < 4; ++mf)
                af[mf] = *(short8*)&Alds[(wr * 64 + mf * 16 + lrow) * LDS_STRIDE + ks * 32 + lk * 8];
#pragma unroll
            for (int nf = 0; nf < 4; ++nf)
                bf[nf] = *(short8*)&Blds[(wc * 64 + nf * 16 + lrow) * LDS_STRIDE + ks * 32 + lk * 8];
#pragma unroll
            for (int mf = 0; mf < 4; ++mf)
#pragma unroll
                for (int nf = 0; nf < 4; ++nf)
                    acc[mf][nf] = __builtin_amdgcn_mfma_f32_16x16x32_bf16(af[mf], bf[nf], acc[mf][nf], 0, 0, 0);
        }
    }

    // epilogue: wave's 64 cols = one output m-row (ntl*2 + wc); store to lp-row TO_M[...]
    int mrow_l = ntl * 2 + wc;
    if (mrow_l < nrows) {
        int lp = d_TO_M[kbase + mrow_l];
        float* op = out + (size_t)lp * CCH;
#pragma unroll
        for (int nf = 0; nf < 4; ++nf) {
            int c = nf * 16 + lrow;
            float bias = 0.f;
            if (blk == 0) bias = b0[mrow_l * 64 + c];
#pragma unroll
            for (int mf = 0; mf < 4; ++mf) {
                int e0 = ebase + wr * 64 + mf * 16 + lk * 4;
#pragma unroll
                for (int j = 0; j < 4; ++j) {
                    int e = e0 + j;
                    if (e < E) op[(size_t)e * XSTRIDE + c] = acc[mf][nf][j] + bias;
                }
            }
        }
    }
}

extern "C" void kernel_launch(void* const* d_in, const int* in_sizes, int n_in,
                              void* d_out, int out_size, void* d_ws, size_t ws_size,
                              hipStream_t stream) {
    const float* x_emb = (const float*)d_in[0];
    // d_in[1] = x_edge: unused by the reference
    const float* W0 = (const float*)d_in[2];
    const float* b0 = (const float*)d_in[3];
    const float* W1 = (const float*)d_in[4];
    const float* W2 = (const float*)d_in[5];
    float* out = (float*)d_out;
    short* ws  = (short*)d_ws;   // bf16 effective weights, 2,400,256 B

    const int E = in_sizes[0] / (NROW * CCH);

    const int prep_total = N0SQ + N1SQ + N2SQ;
    prep_weights<<<(prep_total + 255) / 256, 256, 0, stream>>>(W0, W1, W2, ws);

    const int etiles = (E + 127) / 128;
    const int nwg = etiles * 15;
    so2_gemm<<<nwg, 256, 0, stream>>>(x_emb, b0, (const short*)ws, out, E, nwg);
}